// Round 10
// baseline (203.613 us; speedup 1.0000x reference)
//
#include <hip/hip_runtime.h>

#define NN 20000
#define EE 640000
#define SS 256
#define DD 2000
#define PP 500
#define PHH 100
#define ZSPLIT 25
#define KCH 80
#define SUB 10

typedef unsigned short ushort_t;

__device__ __forceinline__ unsigned short f2bf(float f) {
  unsigned u = __float_as_uint(f);
  unsigned r = (u + 0x7FFFu + ((u >> 16) & 1u)) >> 16;  // RNE
  return (unsigned short)r;
}
__device__ __forceinline__ float lo16(unsigned u) { return __uint_as_float(u << 16); }
__device__ __forceinline__ float hi16(unsigned u) { return __uint_as_float(u & 0xFFFF0000u); }

// ---------- 1. fused roots: meanstd | maskw | zero counts ----------
__global__ __launch_bounds__(256) void k_pre(
    const float* __restrict__ lnc, const float* __restrict__ mi,
    const float* __restrict__ mdat, float* __restrict__ mean,
    float* __restrict__ invstd, const float* __restrict__ Wmp,
    const float* __restrict__ pmask, float* __restrict__ Wt,
    int* __restrict__ counts) {
  int b = blockIdx.x;
  int tx = threadIdx.x, ty = threadIdx.y;
  int tid = ty * 32 + tx;
  if (b < 256) {
    int s = b;
    double sum = 0.0, ssq = 0.0;
    const float4* L = (const float4*)(lnc + (size_t)s * 8000);
    const float4* M = (const float4*)(mi + (size_t)s * 2000);
    const float4* D = (const float4*)(mdat + (size_t)s * 10000);
    for (int i = tid; i < 2000; i += 256) {
      float4 v = L[i];
      sum += (double)v.x + (double)v.y + (double)v.z + (double)v.w;
      ssq += (double)v.x * v.x + (double)v.y * v.y + (double)v.z * v.z + (double)v.w * v.w;
    }
    for (int i = tid; i < 500; i += 256) {
      float4 v = M[i];
      sum += (double)v.x + (double)v.y + (double)v.z + (double)v.w;
      ssq += (double)v.x * v.x + (double)v.y * v.y + (double)v.z * v.z + (double)v.w * v.w;
    }
    for (int i = tid; i < 2500; i += 256) {
      float4 v = D[i];
      sum += (double)v.x + (double)v.y + (double)v.z + (double)v.w;
      ssq += (double)v.x * v.x + (double)v.y * v.y + (double)v.z * v.z + (double)v.w * v.w;
    }
    __shared__ double sm[256], sq[256];
    sm[tid] = sum; sq[tid] = ssq; __syncthreads();
    for (int o = 128; o > 0; o >>= 1) {
      if (tid < o) { sm[tid] += sm[tid + o]; sq[tid] += sq[tid + o]; }
      __syncthreads();
    }
    if (tid == 0) {
      double mu = sm[0] / 20000.0;
      double var = (sq[0] - 20000.0 * mu * mu) / 19999.0;
      mean[s] = (float)mu;
      invstd[s] = (float)(1.0 / sqrt(var));
    }
  } else if (b < 1264) {
    __shared__ float tile[32][33];
    int b2 = b - 256;
    int p0 = (b2 & 15) * 32, d0 = (b2 >> 4) * 32;
    for (int r = ty; r < 32; r += 8) {
      int p = p0 + r, d = d0 + tx;
      float v = 0.f;
      if (p < PP && d < DD) v = Wmp[(size_t)p * DD + d] * pmask[(size_t)p * DD + d];
      tile[r][tx] = v;
    }
    __syncthreads();
    for (int r = ty; r < 32; r += 8) {
      int d = d0 + r, p = p0 + tx;
      if (d < DD) Wt[(size_t)d * 512 + p] = tile[tx][r];
    }
  } else {
    int idx = (b - 1264) * 256 + tid;
    if (idx < NN / 4) {
      uint4 z; z.x = 0; z.y = 0; z.z = 0; z.w = 0;
      ((uint4*)counts)[idx] = z;
    }
  }
}

// ---------- 2. fused: transpose(+rowsum) | degree counts ----------
__global__ __launch_bounds__(256) void k_prep(
    const float* __restrict__ lnc, const float* __restrict__ mi,
    const float* __restrict__ mdat, const float* __restrict__ mean,
    const float* __restrict__ invstd, ushort_t* __restrict__ a_rna,
    float* __restrict__ rowsum4, const int* __restrict__ dst,
    int* __restrict__ counts) {
  int b = blockIdx.x;
  int tx = threadIdx.x, ty = threadIdx.y;
  if (b < 2500) {
    __shared__ float tile[64][33];  // [s][n]
    __shared__ float red[8][33];
    int nb = (b % 625) * 32, sb = (b / 625) * 64;
    int n = nb + tx;
    const float* base; int w, c;
    if (n < 8000)       { base = lnc;  w = 8000;  c = n; }
    else if (n < 10000) { base = mi;   w = 2000;  c = n - 8000; }
    else                { base = mdat; w = 10000; c = n - 10000; }
    for (int r = ty; r < 64; r += 8) {
      int s = sb + r;
      tile[r][tx] = (base[(size_t)s * w + c] - mean[s]) * invstd[s];
    }
    __syncthreads();
    float ps = 0.f;
    for (int r = ty; r < 64; r += 8) ps += tile[r][tx];
    red[ty][tx] = ps;
    __syncthreads();
    if (ty == 0) {
      float t = 0.f;
      #pragma unroll
      for (int j = 0; j < 8; ++j) t += red[j][tx];
      rowsum4[(size_t)(sb >> 6) * NN + nb + tx] = t;
    }
    ushort2* out2 = (ushort2*)a_rna;
    for (int r2 = ty; r2 < 32; r2 += 8) {
      int nn = nb + r2;
      ushort2 v;
      v.x = f2bf(tile[2 * tx][r2]);
      v.y = f2bf(tile[2 * tx + 1][r2]);
      out2[(size_t)nn * 128 + (sb >> 1) + tx] = v;
    }
  } else {
    int e = (b - 2500) * 256 + ty * 32 + tx;
    if (e < EE) atomicAdd(&counts[dst[e]], 1);
  }
}

// ---------- 3. scan (block 0) | a1/a2 finalize (blocks 1..20) ----------
__global__ __launch_bounds__(1024) void k_scan(
    const int* __restrict__ counts, int* __restrict__ offsets, int* __restrict__ cursor,
    const float* __restrict__ rowsum4, const float* __restrict__ attnl,
    const float* __restrict__ attnr, float* __restrict__ a1, float* __restrict__ a2) {
  if (blockIdx.x == 0) {
    __shared__ int sums[1024];
    int t = threadIdx.x;
    int base = t * 20;
    int local[20];
    int s = 0;
    for (int i = 0; i < 20; ++i) {
      int idx = base + i;
      int c = (idx < NN) ? counts[idx] : 0;
      local[i] = s; s += c;
    }
    sums[t] = s; __syncthreads();
    for (int d = 1; d < 1024; d <<= 1) {
      int v = (t >= d) ? sums[t - d] : 0;
      __syncthreads();
      sums[t] += v;
      __syncthreads();
    }
    int prefix = (t > 0) ? sums[t - 1] : 0;
    for (int i = 0; i < 20; ++i) {
      int idx = base + i;
      if (idx < NN) { int o = prefix + local[i]; offsets[idx] = o; cursor[idx] = o; }
    }
    if (t == 1023) offsets[NN] = sums[1023];
  } else {
    int n = (blockIdx.x - 1) * 1024 + threadIdx.x;
    if (n < NN) {
      float t = rowsum4[n] + rowsum4[NN + n] + rowsum4[2 * NN + n] + rowsum4[3 * NN + n];
      a1[n] = attnl[n] * t;
      a2[n] = attnr[n] * t;
    }
  }
}

// ---------- 4. CSR fill with raw (unnormalized) gate ----------
__device__ __forceinline__ float hc_gate(float l) {
  float sg = 1.0f / (1.0f + __expf(-l * 1.5151515151f));
  return fminf(fmaxf(fmaf(sg, 1.2f, -0.1f), 0.0f), 1.0f);
}

__global__ __launch_bounds__(256) void k_fill(
    const int* __restrict__ src, const int* __restrict__ dst,
    const float* __restrict__ a1, const float* __restrict__ a2,
    const float* __restrict__ bias0, int* __restrict__ cursor,
    uint2* __restrict__ csr) {
  int e = blockIdx.x * 256 + threadIdx.x;
  if (e >= EE) return;
  int d = dst[e], s = src[e];
  float a = hc_gate(a1[s] + a2[d] + bias0[0]);
  int slot = atomicAdd(&cursor[d], 1);
  uint2 rec; rec.x = (unsigned)s; rec.y = __float_as_uint(a);
  csr[slot] = rec;
}

// ---------- 5. pass-1 aggregation, column-chunked for L2 residency ----------
// grid (NN/4, 4): blockIdx.y = column chunk (64 bf16 = 128 B per row).
// Wave = 8 groups x 8 lanes; group = edge slot, lane-in-group = 16 B slice.
__global__ __launch_bounds__(256) void k_agg(
    const uint2* __restrict__ csr, const int* __restrict__ offs,
    const ushort_t* __restrict__ in_bf, ushort_t* __restrict__ out_bf,
    float* __restrict__ zinv) {
  int wave = threadIdx.x >> 6, lane = threadIdx.x & 63;
  int grp = lane >> 3, q = lane & 7;
  int n = blockIdx.x * 4 + wave;
  int colbase = blockIdx.y * 8 + q;
  int beg = __builtin_amdgcn_readfirstlane(offs[n]);
  int end = __builtin_amdgcn_readfirstlane(offs[n + 1]);
  const uint4* in4 = (const uint4*)in_bf;
  float acc[8] = {0.f, 0.f, 0.f, 0.f, 0.f, 0.f, 0.f, 0.f};
  float zsum = 0.f;
  int i = beg;
  for (; i + 15 < end; i += 16) {
    uint2 rA = csr[i + grp];
    uint2 rB = csr[i + 8 + grp];
    uint4 vA = in4[(size_t)rA.x * 32 + colbase];
    uint4 vB = in4[(size_t)rB.x * 32 + colbase];
    float gA = __uint_as_float(rA.y), gB = __uint_as_float(rB.y);
    zsum += gA + gB;
    acc[0] += gA * lo16(vA.x) + gB * lo16(vB.x);
    acc[1] += gA * hi16(vA.x) + gB * hi16(vB.x);
    acc[2] += gA * lo16(vA.y) + gB * lo16(vB.y);
    acc[3] += gA * hi16(vA.y) + gB * hi16(vB.y);
    acc[4] += gA * lo16(vA.z) + gB * lo16(vB.z);
    acc[5] += gA * hi16(vA.z) + gB * hi16(vB.z);
    acc[6] += gA * lo16(vA.w) + gB * lo16(vB.w);
    acc[7] += gA * hi16(vA.w) + gB * hi16(vB.w);
  }
  for (; i + 7 < end; i += 8) {
    uint2 rA = csr[i + grp];
    uint4 vA = in4[(size_t)rA.x * 32 + colbase];
    float gA = __uint_as_float(rA.y);
    zsum += gA;
    acc[0] += gA * lo16(vA.x); acc[1] += gA * hi16(vA.x);
    acc[2] += gA * lo16(vA.y); acc[3] += gA * hi16(vA.y);
    acc[4] += gA * lo16(vA.z); acc[5] += gA * hi16(vA.z);
    acc[6] += gA * lo16(vA.w); acc[7] += gA * hi16(vA.w);
  }
  if (i + grp < end) {
    uint2 rA = csr[i + grp];
    uint4 vA = in4[(size_t)rA.x * 32 + colbase];
    float gA = __uint_as_float(rA.y);
    zsum += gA;
    acc[0] += gA * lo16(vA.x); acc[1] += gA * hi16(vA.x);
    acc[2] += gA * lo16(vA.y); acc[3] += gA * hi16(vA.y);
    acc[4] += gA * lo16(vA.z); acc[5] += gA * hi16(vA.z);
    acc[6] += gA * lo16(vA.w); acc[7] += gA * hi16(vA.w);
  }
  #pragma unroll
  for (int j = 0; j < 8; ++j) {
    acc[j] += __shfl_xor(acc[j], 8, 64);
    acc[j] += __shfl_xor(acc[j], 16, 64);
    acc[j] += __shfl_xor(acc[j], 32, 64);
  }
  zsum += __shfl_xor(zsum, 8, 64);
  zsum += __shfl_xor(zsum, 16, 64);
  zsum += __shfl_xor(zsum, 32, 64);
  float inv = (zsum > 0.f) ? 1.0f / zsum : 0.0f;
  if (blockIdx.y == 0 && lane == 0) zinv[n] = inv;
  if (grp == 0) {
    uint4 w;
    w.x = (unsigned)f2bf(acc[0] * inv) | ((unsigned)f2bf(acc[1] * inv) << 16);
    w.y = (unsigned)f2bf(acc[2] * inv) | ((unsigned)f2bf(acc[3] * inv) << 16);
    w.z = (unsigned)f2bf(acc[4] * inv) | ((unsigned)f2bf(acc[5] * inv) << 16);
    w.w = (unsigned)f2bf(acc[6] * inv) | ((unsigned)f2bf(acc[7] * inv) << 16);
    ((uint4*)out_bf)[(size_t)n * 32 + colbase] = w;
  }
}

// ---------- 6. fused pass-2 + x build: xt[d][s] f32 ----------
__global__ __launch_bounds__(256) void k_pass2x(
    const int* __restrict__ dem, const int* __restrict__ offs,
    const uint2* __restrict__ csr, const ushort_t* __restrict__ a_rna,
    const ushort_t* __restrict__ rna1, const float* __restrict__ zinv,
    float* __restrict__ xt) {
  int wave = threadIdx.x >> 6, lane = threadIdx.x & 63;
  int half = lane >> 5, sl = lane & 31;
  int d = blockIdx.x * 4 + wave;
  int nd = dem[d];
  const uint4* ar = (const uint4*)a_rna;
  const uint4* r1 = (const uint4*)rna1;
  int beg = __builtin_amdgcn_readfirstlane(offs[nd]);
  int end = __builtin_amdgcn_readfirstlane(offs[nd + 1]);
  float inv = zinv[nd];
  float acc[8] = {0.f, 0.f, 0.f, 0.f, 0.f, 0.f, 0.f, 0.f};
  int i = beg;
  for (; i + 3 < end; i += 4) {
    uint2 rA = csr[i + half];
    uint2 rB = csr[i + 2 + half];
    uint4 vA = r1[(size_t)rA.x * 32 + sl];
    uint4 vB = r1[(size_t)rB.x * 32 + sl];
    float gA = __uint_as_float(rA.y) * inv, gB = __uint_as_float(rB.y) * inv;
    acc[0] += gA * lo16(vA.x) + gB * lo16(vB.x);
    acc[1] += gA * hi16(vA.x) + gB * hi16(vB.x);
    acc[2] += gA * lo16(vA.y) + gB * lo16(vB.y);
    acc[3] += gA * hi16(vA.y) + gB * hi16(vB.y);
    acc[4] += gA * lo16(vA.z) + gB * lo16(vB.z);
    acc[5] += gA * hi16(vA.z) + gB * hi16(vB.z);
    acc[6] += gA * lo16(vA.w) + gB * lo16(vB.w);
    acc[7] += gA * hi16(vA.w) + gB * hi16(vB.w);
  }
  for (; i + 1 < end; i += 2) {
    uint2 rA = csr[i + half];
    uint4 vA = r1[(size_t)rA.x * 32 + sl];
    float gA = __uint_as_float(rA.y) * inv;
    acc[0] += gA * lo16(vA.x); acc[1] += gA * hi16(vA.x);
    acc[2] += gA * lo16(vA.y); acc[3] += gA * hi16(vA.y);
    acc[4] += gA * lo16(vA.z); acc[5] += gA * hi16(vA.z);
    acc[6] += gA * lo16(vA.w); acc[7] += gA * hi16(vA.w);
  }
  if (i < end && half == 0) {
    uint2 rA = csr[i];
    uint4 vA = r1[(size_t)rA.x * 32 + sl];
    float gA = __uint_as_float(rA.y) * inv;
    acc[0] += gA * lo16(vA.x); acc[1] += gA * hi16(vA.x);
    acc[2] += gA * lo16(vA.y); acc[3] += gA * hi16(vA.y);
    acc[4] += gA * lo16(vA.z); acc[5] += gA * hi16(vA.z);
    acc[6] += gA * lo16(vA.w); acc[7] += gA * hi16(vA.w);
  }
  #pragma unroll
  for (int j = 0; j < 8; ++j) acc[j] += __shfl_xor(acc[j], 32, 64);
  if (half == 0) {
    uint4 va = ar[(size_t)nd * 32 + sl];
    uint4 vb = r1[(size_t)nd * 32 + sl];
    acc[0] += lo16(va.x) + lo16(vb.x); acc[1] += hi16(va.x) + hi16(vb.x);
    acc[2] += lo16(va.y) + lo16(vb.y); acc[3] += hi16(va.y) + hi16(vb.y);
    acc[4] += lo16(va.z) + lo16(vb.z); acc[5] += hi16(va.z) + hi16(vb.z);
    acc[6] += lo16(va.w) + lo16(vb.w); acc[7] += hi16(va.w) + hi16(vb.w);
    float4* xo = (float4*)&xt[(size_t)d * SS + sl * 8];
    float4 w0; w0.x = acc[0]; w0.y = acc[1]; w0.z = acc[2]; w0.w = acc[3];
    float4 w1; w1.x = acc[4]; w1.y = acc[5]; w1.z = acc[6]; w1.w = acc[7];
    xo[0] = w0; xo[1] = w1;
  }
}

// ---------- 7. GEMM1: partial[z][p][s] = Wt-slice^T x xt-slice ----------
__global__ __launch_bounds__(256) void k_gemm1(
    const float* __restrict__ xt, const float* __restrict__ Wt,
    float* __restrict__ partial) {
  __shared__ float As[SUB][64];
  __shared__ float Ws[SUB][68];
  int tid = threadIdx.x;
  int s0 = blockIdx.x * 64, p0 = blockIdx.y * 64, d0 = blockIdx.z * KCH;
  int ts = tid & 15, tp = tid >> 4;
  float acc[4][4];
  #pragma unroll
  for (int i = 0; i < 4; ++i)
    #pragma unroll
    for (int j = 0; j < 4; ++j) acc[i][j] = 0.f;

  for (int kt = 0; kt < KCH / SUB; ++kt) {
    int dd = d0 + kt * SUB;
    #pragma unroll
    for (int i = tid; i < SUB * 64; i += 256) {
      int r = i >> 6, c = i & 63;
      As[r][c] = xt[(size_t)(dd + r) * SS + s0 + c];
    }
    #pragma unroll
    for (int i = tid; i < SUB * 64; i += 256) {
      int r = i >> 6, c = i & 63;
      Ws[r][c] = Wt[(size_t)(dd + r) * 512 + p0 + c];
    }
    __syncthreads();
    #pragma unroll
    for (int kk = 0; kk < SUB; ++kk) {
      float4 a = *(const float4*)&As[kk][ts * 4];
      float4 b = *(const float4*)&Ws[kk][tp * 4];
      acc[0][0] += a.x * b.x; acc[0][1] += a.x * b.y; acc[0][2] += a.x * b.z; acc[0][3] += a.x * b.w;
      acc[1][0] += a.y * b.x; acc[1][1] += a.y * b.y; acc[1][2] += a.y * b.z; acc[1][3] += a.y * b.w;
      acc[2][0] += a.z * b.x; acc[2][1] += a.z * b.y; acc[2][2] += a.z * b.z; acc[2][3] += a.z * b.w;
      acc[3][0] += a.w * b.x; acc[3][1] += a.w * b.y; acc[3][2] += a.w * b.z; acc[3][3] += a.w * b.w;
    }
    __syncthreads();
  }
  float* dstp = partial + (size_t)blockIdx.z * 512 * 256;
  #pragma unroll
  for (int j = 0; j < 4; ++j) {
    int p = p0 + tp * 4 + j;
    float4 w; w.x = acc[0][j]; w.y = acc[1][j]; w.z = acc[2][j]; w.w = acc[3][j];
    *(float4*)&dstp[(size_t)p * 256 + s0 + ts * 4] = w;
  }
}

// ---------- 8. reduce partials + bias + relu (float4) ----------
__global__ __launch_bounds__(256) void k_reduce(
    const float* __restrict__ partial, const float* __restrict__ bmp,
    float* __restrict__ h1t) {
  int idx4 = blockIdx.x * 256 + threadIdx.x;
  if (idx4 >= PP * SS / 4) return;
  int p = idx4 >> 6;  // 64 float4 per p-row
  float b = bmp[p];
  float4 acc; acc.x = b; acc.y = b; acc.z = b; acc.w = b;
  #pragma unroll
  for (int z = 0; z < ZSPLIT; ++z) {
    float4 v = ((const float4*)partial)[(size_t)z * 512 * 64 + idx4];
    acc.x += v.x; acc.y += v.y; acc.z += v.z; acc.w += v.w;
  }
  acc.x = fmaxf(acc.x, 0.f); acc.y = fmaxf(acc.y, 0.f);
  acc.z = fmaxf(acc.z, 0.f); acc.w = fmaxf(acc.w, 0.f);
  ((float4*)h1t)[idx4] = acc;
}

// ---------- 9. h2t[ph][s]: one wave per (ph, 64-s block), 10-way ILP ----------
__global__ __launch_bounds__(64) void k_h2(
    const float* __restrict__ h1t, const float* __restrict__ Wph,
    const float* __restrict__ bph, float* __restrict__ h2t) {
  int ph = blockIdx.x;
  int s = blockIdx.y * 64 + threadIdx.x;
  const float* w = &Wph[(size_t)ph * PP];
  float acc[10];
  #pragma unroll
  for (int j = 0; j < 10; ++j) acc[j] = 0.f;
  for (int k = 0; k < 50; ++k) {
    int p = k * 10;
    #pragma unroll
    for (int j = 0; j < 10; ++j)
      acc[j] = fmaf(h1t[(size_t)(p + j) * SS + s], w[p + j], acc[j]);
  }
  float t = ((acc[0] + acc[1]) + (acc[2] + acc[3])) + ((acc[4] + acc[5]) + (acc[6] + acc[7])) + (acc[8] + acc[9]);
  h2t[(size_t)ph * SS + s] = fmaxf(t + bph[ph], 0.0f);
}

// ---------- 10. out[s,:] = softmax ----------
__global__ __launch_bounds__(256) void k_out(
    const float* __restrict__ h2t, const float* __restrict__ Wpo,
    const float* __restrict__ bpo, float* __restrict__ out) {
  int s = threadIdx.x;
  float o0 = bpo[0], o1 = bpo[1];
  for (int ph = 0; ph < PHH; ++ph) {
    float v = h2t[(size_t)ph * SS + s];
    o0 += v * Wpo[ph];
    o1 += v * Wpo[PHH + ph];
  }
  float mx = fmaxf(o0, o1);
  float e0 = __expf(o0 - mx), e1 = __expf(o1 - mx);
  float inv = 1.0f / (e0 + e1);
  out[2 * s] = e0 * inv;
  out[2 * s + 1] = e1 * inv;
}

extern "C" void kernel_launch(void* const* d_in, const int* in_sizes, int n_in,
                              void* d_out, int out_size, void* d_ws, size_t ws_size,
                              hipStream_t stream) {
  const float* lnc   = (const float*)d_in[0];
  const float* mi    = (const float*)d_in[1];
  const float* mdat  = (const float*)d_in[2];
  const int*   src   = (const int*)d_in[3];
  const int*   dst   = (const int*)d_in[4];
  const int*   dem   = (const int*)d_in[5];
  const float* attnl = (const float*)d_in[6];
  const float* attnr = (const float*)d_in[7];
  const float* bias0 = (const float*)d_in[8];
  const float* pmask = (const float*)d_in[9];
  const float* Wmp   = (const float*)d_in[10];
  const float* bmp   = (const float*)d_in[11];
  const float* Wph   = (const float*)d_in[12];
  const float* bph   = (const float*)d_in[13];
  const float* Wpo   = (const float*)d_in[14];
  const float* bpo   = (const float*)d_in[15];
  float* out = (float*)d_out;

  char* ws = (char*)d_ws;
  size_t off = 0;
  auto alloc = [&](size_t bytes) -> char* {
    char* p = ws + off;
    off += (bytes + 255) & ~(size_t)255;
    return p;
  };
  float*    mean    = (float*)alloc(SS * 4);
  float*    invstd  = (float*)alloc(SS * 4);
  float*    a1      = (float*)alloc(NN * 4);
  float*    a2      = (float*)alloc(NN * 4);
  float*    rowsum4 = (float*)alloc((size_t)4 * NN * 4);
  float*    zinv    = (float*)alloc(NN * 4);
  int*      counts  = (int*)alloc(NN * 4);
  int*      offs    = (int*)alloc((NN + 1) * 4);
  int*      cursor  = (int*)alloc(NN * 4);
  uint2*    csr     = (uint2*)alloc((size_t)EE * 8);
  ushort_t* a_rna   = (ushort_t*)alloc((size_t)NN * SS * 2);
  ushort_t* rna1    = (ushort_t*)alloc((size_t)NN * SS * 2);
  float*    xt      = (float*)alloc((size_t)DD * SS * 4);
  float*    Wt      = (float*)alloc((size_t)DD * 512 * 4);
  float*    partial = (float*)alloc((size_t)ZSPLIT * 512 * 256 * 4);
  float*    h1t     = (float*)alloc((size_t)PP * SS * 4);
  float*    h2t     = (float*)alloc((size_t)PHH * SS * 4);

  k_pre<<<1284, dim3(32, 8), 0, stream>>>(lnc, mi, mdat, mean, invstd, Wmp, pmask, Wt, counts);
  k_prep<<<5000, dim3(32, 8), 0, stream>>>(lnc, mi, mdat, mean, invstd, a_rna, rowsum4, dst, counts);
  k_scan<<<21, 1024, 0, stream>>>(counts, offs, cursor, rowsum4, attnl, attnr, a1, a2);
  k_fill<<<(EE + 255) / 256, 256, 0, stream>>>(src, dst, a1, a2, bias0, cursor, csr);
  k_agg<<<dim3(NN / 4, 4), 256, 0, stream>>>(csr, offs, a_rna, rna1, zinv);
  k_pass2x<<<DD / 4, 256, 0, stream>>>(dem, offs, csr, a_rna, rna1, zinv, xt);
  k_gemm1<<<dim3(SS / 64, 8, ZSPLIT), 256, 0, stream>>>(xt, Wt, partial);
  k_reduce<<<(PP * SS / 4 + 255) / 256, 256, 0, stream>>>(partial, bmp, h1t);
  k_h2<<<dim3(PHH, SS / 64), 64, 0, stream>>>(h1t, Wph, bph, h2t);
  k_out<<<1, SS, 0, stream>>>(h2t, Wpo, bpo, out);
}

// Round 11
// 198.232 us; speedup vs baseline: 1.0271x; 1.0271x over previous
//
#include <hip/hip_runtime.h>

#define NN 20000
#define EE 640000
#define SS 256
#define DD 2000
#define PP 500
#define PHH 100
#define ZSPLIT 25
#define KCH 80
#define SUB 10

typedef unsigned short ushort_t;

__device__ __forceinline__ unsigned short f2bf(float f) {
  unsigned u = __float_as_uint(f);
  unsigned r = (u + 0x7FFFu + ((u >> 16) & 1u)) >> 16;  // RNE
  return (unsigned short)r;
}
__device__ __forceinline__ float lo16(unsigned u) { return __uint_as_float(u << 16); }
__device__ __forceinline__ float hi16(unsigned u) { return __uint_as_float(u & 0xFFFF0000u); }

// ---------- 1. fused roots: meanstd | maskw | zero counts ----------
__global__ __launch_bounds__(256) void k_pre(
    const float* __restrict__ lnc, const float* __restrict__ mi,
    const float* __restrict__ mdat, float* __restrict__ mean,
    float* __restrict__ invstd, const float* __restrict__ Wmp,
    const float* __restrict__ pmask, float* __restrict__ Wt,
    int* __restrict__ counts) {
  int b = blockIdx.x;
  int tx = threadIdx.x, ty = threadIdx.y;
  int tid = ty * 32 + tx;
  if (b < 256) {
    int s = b;
    double sum = 0.0, ssq = 0.0;
    const float4* L = (const float4*)(lnc + (size_t)s * 8000);
    const float4* M = (const float4*)(mi + (size_t)s * 2000);
    const float4* D = (const float4*)(mdat + (size_t)s * 10000);
    for (int i = tid; i < 2000; i += 256) {
      float4 v = L[i];
      sum += (double)v.x + (double)v.y + (double)v.z + (double)v.w;
      ssq += (double)v.x * v.x + (double)v.y * v.y + (double)v.z * v.z + (double)v.w * v.w;
    }
    for (int i = tid; i < 500; i += 256) {
      float4 v = M[i];
      sum += (double)v.x + (double)v.y + (double)v.z + (double)v.w;
      ssq += (double)v.x * v.x + (double)v.y * v.y + (double)v.z * v.z + (double)v.w * v.w;
    }
    for (int i = tid; i < 2500; i += 256) {
      float4 v = D[i];
      sum += (double)v.x + (double)v.y + (double)v.z + (double)v.w;
      ssq += (double)v.x * v.x + (double)v.y * v.y + (double)v.z * v.z + (double)v.w * v.w;
    }
    __shared__ double sm[256], sq[256];
    sm[tid] = sum; sq[tid] = ssq; __syncthreads();
    for (int o = 128; o > 0; o >>= 1) {
      if (tid < o) { sm[tid] += sm[tid + o]; sq[tid] += sq[tid + o]; }
      __syncthreads();
    }
    if (tid == 0) {
      double mu = sm[0] / 20000.0;
      double var = (sq[0] - 20000.0 * mu * mu) / 19999.0;
      mean[s] = (float)mu;
      invstd[s] = (float)(1.0 / sqrt(var));
    }
  } else if (b < 1264) {
    __shared__ float tile[32][33];
    int b2 = b - 256;
    int p0 = (b2 & 15) * 32, d0 = (b2 >> 4) * 32;
    for (int r = ty; r < 32; r += 8) {
      int p = p0 + r, d = d0 + tx;
      float v = 0.f;
      if (p < PP && d < DD) v = Wmp[(size_t)p * DD + d] * pmask[(size_t)p * DD + d];
      tile[r][tx] = v;
    }
    __syncthreads();
    for (int r = ty; r < 32; r += 8) {
      int d = d0 + r, p = p0 + tx;
      if (d < DD) Wt[(size_t)d * 512 + p] = tile[tx][r];
    }
  } else {
    int idx = (b - 1264) * 256 + tid;
    if (idx < NN / 4) {
      uint4 z; z.x = 0; z.y = 0; z.z = 0; z.w = 0;
      ((uint4*)counts)[idx] = z;
    }
  }
}

// ---------- 2. fused: transpose(+rowsum) | degree counts ----------
__global__ __launch_bounds__(256) void k_prep(
    const float* __restrict__ lnc, const float* __restrict__ mi,
    const float* __restrict__ mdat, const float* __restrict__ mean,
    const float* __restrict__ invstd, ushort_t* __restrict__ a_rna,
    float* __restrict__ rowsum4, const int* __restrict__ dst,
    int* __restrict__ counts) {
  int b = blockIdx.x;
  int tx = threadIdx.x, ty = threadIdx.y;
  if (b < 2500) {
    __shared__ float tile[64][33];  // [s][n]
    __shared__ float red[8][33];
    int nb = (b % 625) * 32, sb = (b / 625) * 64;
    int n = nb + tx;
    const float* base; int w, c;
    if (n < 8000)       { base = lnc;  w = 8000;  c = n; }
    else if (n < 10000) { base = mi;   w = 2000;  c = n - 8000; }
    else                { base = mdat; w = 10000; c = n - 10000; }
    for (int r = ty; r < 64; r += 8) {
      int s = sb + r;
      tile[r][tx] = (base[(size_t)s * w + c] - mean[s]) * invstd[s];
    }
    __syncthreads();
    float ps = 0.f;
    for (int r = ty; r < 64; r += 8) ps += tile[r][tx];
    red[ty][tx] = ps;
    __syncthreads();
    if (ty == 0) {
      float t = 0.f;
      #pragma unroll
      for (int j = 0; j < 8; ++j) t += red[j][tx];
      rowsum4[(size_t)(sb >> 6) * NN + nb + tx] = t;
    }
    ushort2* out2 = (ushort2*)a_rna;
    for (int r2 = ty; r2 < 32; r2 += 8) {
      int nn = nb + r2;
      ushort2 v;
      v.x = f2bf(tile[2 * tx][r2]);
      v.y = f2bf(tile[2 * tx + 1][r2]);
      out2[(size_t)nn * 128 + (sb >> 1) + tx] = v;
    }
  } else {
    int e = (b - 2500) * 256 + ty * 32 + tx;
    if (e < EE) atomicAdd(&counts[dst[e]], 1);
  }
}

// ---------- 3. scan (block 0) | a1/a2 finalize (blocks 1..20) ----------
__global__ __launch_bounds__(1024) void k_scan(
    const int* __restrict__ counts, int* __restrict__ offsets, int* __restrict__ cursor,
    const float* __restrict__ rowsum4, const float* __restrict__ attnl,
    const float* __restrict__ attnr, float* __restrict__ a1, float* __restrict__ a2) {
  if (blockIdx.x == 0) {
    __shared__ int sums[1024];
    int t = threadIdx.x;
    int base = t * 20;
    int local[20];
    int s = 0;
    for (int i = 0; i < 20; ++i) {
      int idx = base + i;
      int c = (idx < NN) ? counts[idx] : 0;
      local[i] = s; s += c;
    }
    sums[t] = s; __syncthreads();
    for (int d = 1; d < 1024; d <<= 1) {
      int v = (t >= d) ? sums[t - d] : 0;
      __syncthreads();
      sums[t] += v;
      __syncthreads();
    }
    int prefix = (t > 0) ? sums[t - 1] : 0;
    for (int i = 0; i < 20; ++i) {
      int idx = base + i;
      if (idx < NN) { int o = prefix + local[i]; offsets[idx] = o; cursor[idx] = o; }
    }
    if (t == 1023) offsets[NN] = sums[1023];
  } else {
    int n = (blockIdx.x - 1) * 1024 + threadIdx.x;
    if (n < NN) {
      float t = rowsum4[n] + rowsum4[NN + n] + rowsum4[2 * NN + n] + rowsum4[3 * NN + n];
      a1[n] = attnl[n] * t;
      a2[n] = attnr[n] * t;
    }
  }
}

// ---------- 4. CSR fill with raw (unnormalized) gate ----------
__device__ __forceinline__ float hc_gate(float l) {
  float sg = 1.0f / (1.0f + __expf(-l * 1.5151515151f));
  return fminf(fmaxf(fmaf(sg, 1.2f, -0.1f), 0.0f), 1.0f);
}

__global__ __launch_bounds__(256) void k_fill(
    const int* __restrict__ src, const int* __restrict__ dst,
    const float* __restrict__ a1, const float* __restrict__ a2,
    const float* __restrict__ bias0, int* __restrict__ cursor,
    uint2* __restrict__ csr) {
  int e = blockIdx.x * 256 + threadIdx.x;
  if (e >= EE) return;
  int d = dst[e], s = src[e];
  float a = hc_gate(a1[s] + a2[d] + bias0[0]);
  int slot = atomicAdd(&cursor[d], 1);
  uint2 rec; rec.x = (unsigned)s; rec.y = __float_as_uint(a);
  csr[slot] = rec;
}

// ---------- 5. pass-1 aggregation, single-pass z, 16-deep pipeline ----------
__global__ __launch_bounds__(256) void k_agg(
    const uint2* __restrict__ csr, const int* __restrict__ offs,
    const ushort_t* __restrict__ in_bf, ushort_t* __restrict__ out_bf,
    float* __restrict__ zinv) {
  int wave = threadIdx.x >> 6, lane = threadIdx.x & 63;
  int half = lane >> 5, sl = lane & 31;
  int n = blockIdx.x * 4 + wave;
  int beg = __builtin_amdgcn_readfirstlane(offs[n]);
  int end = __builtin_amdgcn_readfirstlane(offs[n + 1]);

  const uint4* in4 = (const uint4*)in_bf;
  float acc[8] = {0.f, 0.f, 0.f, 0.f, 0.f, 0.f, 0.f, 0.f};
  float zsum = 0.f;
  int i = beg;
  for (; i + 15 < end; i += 16) {
    uint2 r[8]; uint4 v[8];
    #pragma unroll
    for (int j = 0; j < 8; ++j) r[j] = csr[i + 2 * j + half];
    #pragma unroll
    for (int j = 0; j < 8; ++j) v[j] = in4[(size_t)r[j].x * 32 + sl];
    #pragma unroll
    for (int j = 0; j < 8; ++j) {
      float g = __uint_as_float(r[j].y);
      zsum += g;
      acc[0] += g * lo16(v[j].x); acc[1] += g * hi16(v[j].x);
      acc[2] += g * lo16(v[j].y); acc[3] += g * hi16(v[j].y);
      acc[4] += g * lo16(v[j].z); acc[5] += g * hi16(v[j].z);
      acc[6] += g * lo16(v[j].w); acc[7] += g * hi16(v[j].w);
    }
  }
  for (; i + 3 < end; i += 4) {
    uint2 rA = csr[i + half];
    uint2 rB = csr[i + 2 + half];
    uint4 vA = in4[(size_t)rA.x * 32 + sl];
    uint4 vB = in4[(size_t)rB.x * 32 + sl];
    float gA = __uint_as_float(rA.y), gB = __uint_as_float(rB.y);
    zsum += gA + gB;
    acc[0] += gA * lo16(vA.x) + gB * lo16(vB.x);
    acc[1] += gA * hi16(vA.x) + gB * hi16(vB.x);
    acc[2] += gA * lo16(vA.y) + gB * lo16(vB.y);
    acc[3] += gA * hi16(vA.y) + gB * hi16(vB.y);
    acc[4] += gA * lo16(vA.z) + gB * lo16(vB.z);
    acc[5] += gA * hi16(vA.z) + gB * hi16(vB.z);
    acc[6] += gA * lo16(vA.w) + gB * lo16(vB.w);
    acc[7] += gA * hi16(vA.w) + gB * hi16(vB.w);
  }
  for (; i + 1 < end; i += 2) {
    uint2 rA = csr[i + half];
    uint4 vA = in4[(size_t)rA.x * 32 + sl];
    float gA = __uint_as_float(rA.y);
    zsum += gA;
    acc[0] += gA * lo16(vA.x); acc[1] += gA * hi16(vA.x);
    acc[2] += gA * lo16(vA.y); acc[3] += gA * hi16(vA.y);
    acc[4] += gA * lo16(vA.z); acc[5] += gA * hi16(vA.z);
    acc[6] += gA * lo16(vA.w); acc[7] += gA * hi16(vA.w);
  }
  if (i < end && half == 0) {
    uint2 rA = csr[i];
    uint4 vA = in4[(size_t)rA.x * 32 + sl];
    float gA = __uint_as_float(rA.y);
    zsum += gA;
    acc[0] += gA * lo16(vA.x); acc[1] += gA * hi16(vA.x);
    acc[2] += gA * lo16(vA.y); acc[3] += gA * hi16(vA.y);
    acc[4] += gA * lo16(vA.z); acc[5] += gA * hi16(vA.z);
    acc[6] += gA * lo16(vA.w); acc[7] += gA * hi16(vA.w);
  }
  #pragma unroll
  for (int j = 0; j < 8; ++j) acc[j] += __shfl_xor(acc[j], 32, 64);
  float z = zsum + __shfl_xor(zsum, 32, 64);
  float inv = (z > 0.f) ? 1.0f / z : 0.0f;
  if (lane == 0) zinv[n] = inv;
  if (half == 0) {
    uint4 w;
    w.x = (unsigned)f2bf(acc[0] * inv) | ((unsigned)f2bf(acc[1] * inv) << 16);
    w.y = (unsigned)f2bf(acc[2] * inv) | ((unsigned)f2bf(acc[3] * inv) << 16);
    w.z = (unsigned)f2bf(acc[4] * inv) | ((unsigned)f2bf(acc[5] * inv) << 16);
    w.w = (unsigned)f2bf(acc[6] * inv) | ((unsigned)f2bf(acc[7] * inv) << 16);
    ((uint4*)out_bf)[(size_t)n * 32 + sl] = w;
  }
}

// ---------- 6. fused pass-2 + x build: xt[d][s] f32 ----------
__global__ __launch_bounds__(256) void k_pass2x(
    const int* __restrict__ dem, const int* __restrict__ offs,
    const uint2* __restrict__ csr, const ushort_t* __restrict__ a_rna,
    const ushort_t* __restrict__ rna1, const float* __restrict__ zinv,
    float* __restrict__ xt) {
  int wave = threadIdx.x >> 6, lane = threadIdx.x & 63;
  int half = lane >> 5, sl = lane & 31;
  int d = blockIdx.x * 4 + wave;
  int nd = dem[d];
  const uint4* ar = (const uint4*)a_rna;
  const uint4* r1 = (const uint4*)rna1;
  int beg = __builtin_amdgcn_readfirstlane(offs[nd]);
  int end = __builtin_amdgcn_readfirstlane(offs[nd + 1]);
  float inv = zinv[nd];
  float acc[8] = {0.f, 0.f, 0.f, 0.f, 0.f, 0.f, 0.f, 0.f};
  int i = beg;
  for (; i + 3 < end; i += 4) {
    uint2 rA = csr[i + half];
    uint2 rB = csr[i + 2 + half];
    uint4 vA = r1[(size_t)rA.x * 32 + sl];
    uint4 vB = r1[(size_t)rB.x * 32 + sl];
    float gA = __uint_as_float(rA.y) * inv, gB = __uint_as_float(rB.y) * inv;
    acc[0] += gA * lo16(vA.x) + gB * lo16(vB.x);
    acc[1] += gA * hi16(vA.x) + gB * hi16(vB.x);
    acc[2] += gA * lo16(vA.y) + gB * lo16(vB.y);
    acc[3] += gA * hi16(vA.y) + gB * hi16(vB.y);
    acc[4] += gA * lo16(vA.z) + gB * lo16(vB.z);
    acc[5] += gA * hi16(vA.z) + gB * hi16(vB.z);
    acc[6] += gA * lo16(vA.w) + gB * lo16(vB.w);
    acc[7] += gA * hi16(vA.w) + gB * hi16(vB.w);
  }
  for (; i + 1 < end; i += 2) {
    uint2 rA = csr[i + half];
    uint4 vA = r1[(size_t)rA.x * 32 + sl];
    float gA = __uint_as_float(rA.y) * inv;
    acc[0] += gA * lo16(vA.x); acc[1] += gA * hi16(vA.x);
    acc[2] += gA * lo16(vA.y); acc[3] += gA * hi16(vA.y);
    acc[4] += gA * lo16(vA.z); acc[5] += gA * hi16(vA.z);
    acc[6] += gA * lo16(vA.w); acc[7] += gA * hi16(vA.w);
  }
  if (i < end && half == 0) {
    uint2 rA = csr[i];
    uint4 vA = r1[(size_t)rA.x * 32 + sl];
    float gA = __uint_as_float(rA.y) * inv;
    acc[0] += gA * lo16(vA.x); acc[1] += gA * hi16(vA.x);
    acc[2] += gA * lo16(vA.y); acc[3] += gA * hi16(vA.y);
    acc[4] += gA * lo16(vA.z); acc[5] += gA * hi16(vA.z);
    acc[6] += gA * lo16(vA.w); acc[7] += gA * hi16(vA.w);
  }
  #pragma unroll
  for (int j = 0; j < 8; ++j) acc[j] += __shfl_xor(acc[j], 32, 64);
  if (half == 0) {
    uint4 va = ar[(size_t)nd * 32 + sl];
    uint4 vb = r1[(size_t)nd * 32 + sl];
    acc[0] += lo16(va.x) + lo16(vb.x); acc[1] += hi16(va.x) + hi16(vb.x);
    acc[2] += lo16(va.y) + lo16(vb.y); acc[3] += hi16(va.y) + hi16(vb.y);
    acc[4] += lo16(va.z) + lo16(vb.z); acc[5] += hi16(va.z) + hi16(vb.z);
    acc[6] += lo16(va.w) + lo16(vb.w); acc[7] += hi16(va.w) + hi16(vb.w);
    float4* xo = (float4*)&xt[(size_t)d * SS + sl * 8];
    float4 w0; w0.x = acc[0]; w0.y = acc[1]; w0.z = acc[2]; w0.w = acc[3];
    float4 w1; w1.x = acc[4]; w1.y = acc[5]; w1.z = acc[6]; w1.w = acc[7];
    xo[0] = w0; xo[1] = w1;
  }
}

// ---------- 7. GEMM1: partial[z][p][s] = Wt-slice^T x xt-slice ----------
__global__ __launch_bounds__(256) void k_gemm1(
    const float* __restrict__ xt, const float* __restrict__ Wt,
    float* __restrict__ partial) {
  __shared__ float As[SUB][64];
  __shared__ float Ws[SUB][68];
  int tid = threadIdx.x;
  int s0 = blockIdx.x * 64, p0 = blockIdx.y * 64, d0 = blockIdx.z * KCH;
  int ts = tid & 15, tp = tid >> 4;
  float acc[4][4];
  #pragma unroll
  for (int i = 0; i < 4; ++i)
    #pragma unroll
    for (int j = 0; j < 4; ++j) acc[i][j] = 0.f;

  for (int kt = 0; kt < KCH / SUB; ++kt) {
    int dd = d0 + kt * SUB;
    #pragma unroll
    for (int i = tid; i < SUB * 64; i += 256) {
      int r = i >> 6, c = i & 63;
      As[r][c] = xt[(size_t)(dd + r) * SS + s0 + c];
    }
    #pragma unroll
    for (int i = tid; i < SUB * 64; i += 256) {
      int r = i >> 6, c = i & 63;
      Ws[r][c] = Wt[(size_t)(dd + r) * 512 + p0 + c];
    }
    __syncthreads();
    #pragma unroll
    for (int kk = 0; kk < SUB; ++kk) {
      float4 a = *(const float4*)&As[kk][ts * 4];
      float4 b = *(const float4*)&Ws[kk][tp * 4];
      acc[0][0] += a.x * b.x; acc[0][1] += a.x * b.y; acc[0][2] += a.x * b.z; acc[0][3] += a.x * b.w;
      acc[1][0] += a.y * b.x; acc[1][1] += a.y * b.y; acc[1][2] += a.y * b.z; acc[1][3] += a.y * b.w;
      acc[2][0] += a.z * b.x; acc[2][1] += a.z * b.y; acc[2][2] += a.z * b.z; acc[2][3] += a.z * b.w;
      acc[3][0] += a.w * b.x; acc[3][1] += a.w * b.y; acc[3][2] += a.w * b.z; acc[3][3] += a.w * b.w;
    }
    __syncthreads();
  }
  float* dstp = partial + (size_t)blockIdx.z * 512 * 256;
  #pragma unroll
  for (int j = 0; j < 4; ++j) {
    int p = p0 + tp * 4 + j;
    float4 w; w.x = acc[0][j]; w.y = acc[1][j]; w.z = acc[2][j]; w.w = acc[3][j];
    *(float4*)&dstp[(size_t)p * 256 + s0 + ts * 4] = w;
  }
}

// ---------- 8. reduce partials + bias + relu (float4) ----------
__global__ __launch_bounds__(256) void k_reduce(
    const float* __restrict__ partial, const float* __restrict__ bmp,
    float* __restrict__ h1t) {
  int idx4 = blockIdx.x * 256 + threadIdx.x;
  if (idx4 >= PP * SS / 4) return;
  int p = idx4 >> 6;  // 64 float4 per p-row
  float b = bmp[p];
  float4 acc; acc.x = b; acc.y = b; acc.z = b; acc.w = b;
  #pragma unroll
  for (int z = 0; z < ZSPLIT; ++z) {
    float4 v = ((const float4*)partial)[(size_t)z * 512 * 64 + idx4];
    acc.x += v.x; acc.y += v.y; acc.z += v.z; acc.w += v.w;
  }
  acc.x = fmaxf(acc.x, 0.f); acc.y = fmaxf(acc.y, 0.f);
  acc.z = fmaxf(acc.z, 0.f); acc.w = fmaxf(acc.w, 0.f);
  ((float4*)h1t)[idx4] = acc;
}

// ---------- 9. h2t[ph][s]: one wave per (ph, 64-s block), 10-way ILP ----------
__global__ __launch_bounds__(64) void k_h2(
    const float* __restrict__ h1t, const float* __restrict__ Wph,
    const float* __restrict__ bph, float* __restrict__ h2t) {
  int ph = blockIdx.x;
  int s = blockIdx.y * 64 + threadIdx.x;
  const float* w = &Wph[(size_t)ph * PP];
  float acc[10];
  #pragma unroll
  for (int j = 0; j < 10; ++j) acc[j] = 0.f;
  for (int k = 0; k < 50; ++k) {
    int p = k * 10;
    #pragma unroll
    for (int j = 0; j < 10; ++j)
      acc[j] = fmaf(h1t[(size_t)(p + j) * SS + s], w[p + j], acc[j]);
  }
  float t = ((acc[0] + acc[1]) + (acc[2] + acc[3])) + ((acc[4] + acc[5]) + (acc[6] + acc[7])) + (acc[8] + acc[9]);
  h2t[(size_t)ph * SS + s] = fmaxf(t + bph[ph], 0.0f);
}

// ---------- 10. out[s,:] = softmax ----------
__global__ __launch_bounds__(256) void k_out(
    const float* __restrict__ h2t, const float* __restrict__ Wpo,
    const float* __restrict__ bpo, float* __restrict__ out) {
  int s = threadIdx.x;
  float o0 = bpo[0], o1 = bpo[1];
  for (int ph = 0; ph < PHH; ++ph) {
    float v = h2t[(size_t)ph * SS + s];
    o0 += v * Wpo[ph];
    o1 += v * Wpo[PHH + ph];
  }
  float mx = fmaxf(o0, o1);
  float e0 = __expf(o0 - mx), e1 = __expf(o1 - mx);
  float inv = 1.0f / (e0 + e1);
  out[2 * s] = e0 * inv;
  out[2 * s + 1] = e1 * inv;
}

extern "C" void kernel_launch(void* const* d_in, const int* in_sizes, int n_in,
                              void* d_out, int out_size, void* d_ws, size_t ws_size,
                              hipStream_t stream) {
  const float* lnc   = (const float*)d_in[0];
  const float* mi    = (const float*)d_in[1];
  const float* mdat  = (const float*)d_in[2];
  const int*   src   = (const int*)d_in[3];
  const int*   dst   = (const int*)d_in[4];
  const int*   dem   = (const int*)d_in[5];
  const float* attnl = (const float*)d_in[6];
  const float* attnr = (const float*)d_in[7];
  const float* bias0 = (const float*)d_in[8];
  const float* pmask = (const float*)d_in[9];
  const float* Wmp   = (const float*)d_in[10];
  const float* bmp   = (const float*)d_in[11];
  const float* Wph   = (const float*)d_in[12];
  const float* bph   = (const float*)d_in[13];
  const float* Wpo   = (const float*)d_in[14];
  const float* bpo   = (const float*)d_in[15];
  float* out = (float*)d_out;

  char* ws = (char*)d_ws;
  size_t off = 0;
  auto alloc = [&](size_t bytes) -> char* {
    char* p = ws + off;
    off += (bytes + 255) & ~(size_t)255;
    return p;
  };
  float*    mean    = (float*)alloc(SS * 4);
  float*    invstd  = (float*)alloc(SS * 4);
  float*    a1      = (float*)alloc(NN * 4);
  float*    a2      = (float*)alloc(NN * 4);
  float*    rowsum4 = (float*)alloc((size_t)4 * NN * 4);
  float*    zinv    = (float*)alloc(NN * 4);
  int*      counts  = (int*)alloc(NN * 4);
  int*      offs    = (int*)alloc((NN + 1) * 4);
  int*      cursor  = (int*)alloc(NN * 4);
  uint2*    csr     = (uint2*)alloc((size_t)EE * 8);
  ushort_t* a_rna   = (ushort_t*)alloc((size_t)NN * SS * 2);
  ushort_t* rna1    = (ushort_t*)alloc((size_t)NN * SS * 2);
  float*    xt      = (float*)alloc((size_t)DD * SS * 4);
  float*    Wt      = (float*)alloc((size_t)DD * 512 * 4);
  float*    partial = (float*)alloc((size_t)ZSPLIT * 512 * 256 * 4);
  float*    h1t     = (float*)alloc((size_t)PP * SS * 4);
  float*    h2t     = (float*)alloc((size_t)PHH * SS * 4);

  k_pre<<<1284, dim3(32, 8), 0, stream>>>(lnc, mi, mdat, mean, invstd, Wmp, pmask, Wt, counts);
  k_prep<<<5000, dim3(32, 8), 0, stream>>>(lnc, mi, mdat, mean, invstd, a_rna, rowsum4, dst, counts);
  k_scan<<<21, 1024, 0, stream>>>(counts, offs, cursor, rowsum4, attnl, attnr, a1, a2);
  k_fill<<<(EE + 255) / 256, 256, 0, stream>>>(src, dst, a1, a2, bias0, cursor, csr);
  k_agg<<<NN / 4, 256, 0, stream>>>(csr, offs, a_rna, rna1, zinv);
  k_pass2x<<<DD / 4, 256, 0, stream>>>(dem, offs, csr, a_rna, rna1, zinv, xt);
  k_gemm1<<<dim3(SS / 64, 8, ZSPLIT), 256, 0, stream>>>(xt, Wt, partial);
  k_reduce<<<(PP * SS / 4 + 255) / 256, 256, 0, stream>>>(partial, bmp, h1t);
  k_h2<<<dim3(PHH, SS / 64), 64, 0, stream>>>(h1t, Wph, bph, h2t);
  k_out<<<1, SS, 0, stream>>>(h2t, Wpo, bpo, out);
}